// Round 8
// baseline (661.903 us; speedup 1.0000x reference)
//
#include <hip/hip_runtime.h>
#include <math.h>

#define BB 64
#define HH 512
#define VV 50000
#define LL 400
#define MM 128
#define DD 64
#define HC 260
#define EPSF 1e-8f

typedef __attribute__((ext_vector_type(8))) short bf16x8;
typedef __attribute__((ext_vector_type(4))) float f32x4;
typedef __attribute__((address_space(1))) const void CGV;   // global src for global_load_lds
typedef __attribute__((address_space(3))) void LV;          // lds dst for global_load_lds

__device__ __forceinline__ float sigmoidf(float x){ return 1.0f/(1.0f+expf(-x)); }
__device__ __forceinline__ unsigned short bf16_rne(float f){
  unsigned u = __float_as_uint(f);
  return (unsigned short)((u + 0x7fffu + ((u >> 16) & 1u)) >> 16);
}
__device__ __forceinline__ float wave_max(float v){
  #pragma unroll
  for(int o=32;o;o>>=1) v = fmaxf(v, __shfl_xor(v,o));
  return v;
}
__device__ __forceinline__ float wave_sum(float v){
  #pragma unroll
  for(int o=32;o;o>>=1) v += __shfl_xor(v,o);
  return v;
}
__device__ __forceinline__ float dot4(float4 w, float4 a){
  return w.x*a.x + w.y*a.y + w.z*a.z + w.w*a.w;
}

// =====================================================================================
// Layout convention: "T4" = activation A(64,K) stored as float4 grid [K/4][64]:
//   T4[kq*64 + b] = { A[b][4kq], A[b][4kq+1], A[b][4kq+2], A[b][4kq+3] }
// "T" (plain)     = A_T[k*64 + b] = A[b][k]
// Batch-lane GEMV: lane=b, wave-uniform row n; weights broadcast (read once chip-wide).
// WORKSPACE NOTE: U (attn partials) aliases memT4 — memT4 dead after k_blgA [2], U
// first written in k_attn_part [5]. Total ws = 1,020,608 floats (< round-0's 1,038,016
// proven-safe high-water mark).
// =====================================================================================

// ---------------- [1] pack: embT4,h0T4,c0T4,c0Tp, rhInT4,whInT4, rcT,wcT, memT4 -------
__global__ __launch_bounds__(256) void k_pack(const int* __restrict__ ids,
    const float* __restrict__ emb, const float* __restrict__ h0,
    const float* __restrict__ c0, const float* __restrict__ read_h,
    const float* __restrict__ write_h, const float* __restrict__ read_c,
    const float* __restrict__ write_c, const float* __restrict__ mem,
    float4* __restrict__ embT4, float4* __restrict__ h0T4, float4* __restrict__ c0T4,
    float* __restrict__ c0Tp, float4* __restrict__ rhInT4, float4* __restrict__ whInT4,
    float* __restrict__ rcT, float* __restrict__ wcT, float4* __restrict__ memT4){
  int t = blockIdx.x*256 + threadIdx.x;
  if (t < 8192){                       // emb/h0/c0: (b, kq<128)
    int b = t & 63, kq = t >> 6;
    float4 e = ((const float4*)emb)[(long)ids[b]*128 + kq];
    float4 h = ((const float4*)h0)[b*128 + kq];
    float4 c = ((const float4*)c0)[b*128 + kq];
    embT4[t] = e; h0T4[t] = h; c0T4[t] = c;
    c0Tp[(4*kq+0)*64+b] = c.x; c0Tp[(4*kq+1)*64+b] = c.y;
    c0Tp[(4*kq+2)*64+b] = c.z; c0Tp[(4*kq+3)*64+b] = c.w;
  } else if (t < 16512){               // read_h/write_h: (b, kq<65)
    int s = t - 8192;
    int which = s >= 4160; int u = which ? s-4160 : s;
    int b = u & 63, kq = u >> 6;
    float4 v = ((const float4*)(which ? write_h : read_h))[b*65 + kq];
    (which ? whInT4 : rhInT4)[u] = v;
  } else if (t < 49792){               // read_c/write_c plain T: (b, j<260)
    int s = t - 16512;
    int which = s >= 16640; int u = which ? s-16640 : s;
    int b = u & 63, j = u >> 6;
    (which ? wcT : rcT)[j*64+b] = (which ? write_c : read_c)[b*260 + j];
  } else if (t < 180864){              // mem: (b, kq<2048)
    int u = t - 49792;
    int b = u & 63, kq = u >> 6;
    memT4[u] = ((const float4*)mem)[b*2048 + kq];
  }
}

// ---------------- [2] blgA: iaT(400,K1024) + tsT(400,K512) + preT(128,K8704) ----------
__global__ __launch_bounds__(256) void k_blgA(const float4* __restrict__ embT4,
    const float4* __restrict__ h0T4, const float4* __restrict__ c0T4,
    const float4* __restrict__ memT4,
    const float* __restrict__ attn_W, const float* __restrict__ attn_b,
    const float* __restrict__ state_W,
    const float* __restrict__ rpre_W, const float* __restrict__ wpre_W,
    const float* __restrict__ rpre_b, const float* __restrict__ wpre_b,
    float* __restrict__ iaT, float* __restrict__ tsT, float* __restrict__ preT){
  int lane = threadIdx.x & 63;
  int gw = __builtin_amdgcn_readfirstlane(blockIdx.x*4 + (threadIdx.x >> 6));
  if (gw < 400){
    int n = gw;
    const float4* W4 = (const float4*)attn_W + (long)n*256;
    float a0=0.f,a1=0.f,a2=0.f,a3=0.f;
    #pragma unroll 8
    for (int i = 0; i < 128; i++){
      float4 a = embT4[i*64+lane]; float4 w = W4[i];
      a0 += w.x*a.x; a1 += w.y*a.y; a2 += w.z*a.z; a3 += w.w*a.w;
    }
    #pragma unroll 8
    for (int i = 0; i < 128; i++){
      float4 a = h0T4[i*64+lane]; float4 w = W4[128+i];
      a0 += w.x*a.x; a1 += w.y*a.y; a2 += w.z*a.z; a3 += w.w*a.w;
    }
    iaT[n*64+lane] = (a0+a1)+(a2+a3) + attn_b[n];
  } else if (gw < 800){
    int n = gw - 400;
    const float4* W4 = (const float4*)state_W + (long)n*128;
    float a0=0.f,a1=0.f,a2=0.f,a3=0.f;
    #pragma unroll 8
    for (int i = 0; i < 128; i++){
      float4 a = c0T4[i*64+lane]; float4 w = W4[i];
      a0 += w.x*a.x; a1 += w.y*a.y; a2 += w.z*a.z; a3 += w.w*a.w;
    }
    tsT[n*64+lane] = (a0+a1)+(a2+a3);
  } else {
    int r = gw - 800;                  // 0..127
    int which = r >> 6, n = r & 63;
    const float4* W4 = (const float4*)(which ? wpre_W : rpre_W) + (long)n*2176;
    float a0=0.f,a1=0.f,a2=0.f,a3=0.f;
    #pragma unroll 8
    for (int i = 0; i < 128; i++){
      float4 a = h0T4[i*64+lane]; float4 w = W4[i];
      a0 += w.x*a.x; a1 += w.y*a.y; a2 += w.z*a.z; a3 += w.w*a.w;
    }
    #pragma unroll 8
    for (int i = 0; i < 2048; i++){
      float4 a = memT4[i*64+lane]; float4 w = W4[128+i];
      a0 += w.x*a.x; a1 += w.y*a.y; a2 += w.z*a.z; a3 += w.w*a.w;
    }
    preT[r*64+lane] = (a0+a1)+(a2+a3) + (which ? wpre_b : rpre_b)[n];
  }
}

// ---------------- [3] covia: coviaT4 = (cov+ia) in T4; ncov = cov+ia (standard) -------
__global__ void k_covia(const float* __restrict__ cov, const float* __restrict__ iaT,
                        float4* __restrict__ coviaT4, float4* __restrict__ ncov4){
  int t = blockIdx.x*256 + threadIdx.x;      // 6400
  if (t >= 6400) return;
  int b = t & 63, kq = t >> 6;
  float4 c = ((const float4*)cov)[b*100 + kq];
  float4 v;
  v.x = c.x + iaT[(4*kq+0)*64+b];
  v.y = c.y + iaT[(4*kq+1)*64+b];
  v.z = c.z + iaT[(4*kq+2)*64+b];
  v.w = c.w + iaT[(4*kq+3)*64+b];
  coviaT4[kq*64+b] = v;
  ncov4[b*100+kq] = v;
}

// ---------------- [4] blg tc: tcT(400, K400) over coviaT4 ----------------
__global__ __launch_bounds__(256) void k_blg_tc(const float4* __restrict__ coviaT4,
    const float* __restrict__ cov_W, float* __restrict__ tcT){
  int lane = threadIdx.x & 63;
  int n = __builtin_amdgcn_readfirstlane(blockIdx.x*4 + (threadIdx.x >> 6));
  const float4* W4 = (const float4*)cov_W + (long)n*100;
  float a0=0.f,a1=0.f,a2=0.f,a3=0.f;
  #pragma unroll 4
  for (int i = 0; i < 100; i++){
    float4 a = coviaT4[i*64+lane]; float4 w = W4[i];
    a0 += w.x*a.x; a1 += w.y*a.y; a2 += w.z*a.z; a3 += w.w*a.w;
  }
  tcT[n*64+lane] = (a0+a1)+(a2+a3);
}

// ---------------- [5] attn partials, inline softmax (T-form score reads) --------------
__global__ __launch_bounds__(256) void k_attn_part(const float* __restrict__ iaT,
                                                   const float* __restrict__ tsT,
                                                   const float* __restrict__ tcT,
                                                   const float* __restrict__ enc,
                                                   float* __restrict__ part){
  int b = blockIdx.x, lc = blockIdx.y, t = threadIdx.x;
  __shared__ float sh[400];
  __shared__ float sm[4], ss[4];
  int i0 = t, i1 = t + 256;
  float x0 = iaT[i0*64+b] + tsT[i0*64+b] + tcT[i0*64+b];
  float x1 = (i1 < LL) ? (iaT[i1*64+b] + tsT[i1*64+b] + tcT[i1*64+b]) : -INFINITY;
  float m = wave_max(fmaxf(x0, x1));
  if ((t & 63) == 0) sm[t>>6] = m;
  __syncthreads();
  m = fmaxf(fmaxf(sm[0], sm[1]), fmaxf(sm[2], sm[3]));
  float e0 = expf(x0 - m);
  float e1 = (i1 < LL) ? expf(x1 - m) : 0.0f;
  sh[i0] = e0;
  if (i1 < LL) sh[i1] = e1;
  float s = wave_sum(e0 + e1);
  if ((t & 63) == 0) ss[t>>6] = s;
  __syncthreads();
  float inv = 1.0f / (ss[0] + ss[1] + ss[2] + ss[3]);
  const float* eb = enc + ((long)b*LL + lc*25)*HH;
  float a0 = 0.f, a1 = 0.f;
  for (int l = 0; l < 25; l++){
    float a = sh[lc*25 + l] * inv;
    a0 += a * eb[(long)l*HH + t];
    a1 += a * eb[(long)l*HH + t + 256];
  }
  part[((b*16 + lc) << 9) + t]       = a0;
  part[((b*16 + lc) << 9) + t + 256] = a1;
}

// ---------------- [6] attn reduce -> attnT4 ----------------
__global__ void k_attn_reduce(const float4* __restrict__ part4, float4* __restrict__ attnT4){
  int t = blockIdx.x*256 + threadIdx.x;      // 8192
  int b = t & 63, hq = t >> 6;               // hq<128
  float4 s = {0.f,0.f,0.f,0.f};
  #pragma unroll
  for (int lc = 0; lc < 16; lc++){
    float4 p = part4[((b*16+lc)<<7) + hq];
    s.x += p.x; s.y += p.y; s.z += p.z; s.w += p.w;
  }
  attnT4[hq*64 + b] = s;
}

// ---------------- [7] blgB: comb(512,K1024) + gates+LSTM(520 units, K324) -------------
__global__ __launch_bounds__(256) void k_blgB(const float4* __restrict__ embT4,
    const float4* __restrict__ attnT4, const float* __restrict__ comb_W,
    const float* __restrict__ comb_b, const float* __restrict__ preT,
    const float4* __restrict__ rhInT4, const float4* __restrict__ whInT4,
    const float* __restrict__ rcT, const float* __restrict__ wcT,
    const float* __restrict__ rWih, const float* __restrict__ rWhh,
    const float* __restrict__ rbih, const float* __restrict__ rbhh,
    const float* __restrict__ wWih, const float* __restrict__ wWhh,
    const float* __restrict__ wbih, const float* __restrict__ wbhh,
    float* __restrict__ xc3T, float* __restrict__ rhT, float* __restrict__ whT){
  int lane = threadIdx.x & 63;
  int gw = __builtin_amdgcn_readfirstlane(blockIdx.x*4 + (threadIdx.x >> 6));
  if (gw < 512){                      // comb -> xc3T rows 0..511
    int n = gw;
    const float4* W4 = (const float4*)comb_W + (long)n*256;
    float a0=0.f,a1=0.f,a2=0.f,a3=0.f;
    #pragma unroll 8
    for (int i = 0; i < 128; i++){
      float4 a = embT4[i*64+lane]; float4 w = W4[i];
      a0 += w.x*a.x; a1 += w.y*a.y; a2 += w.z*a.z; a3 += w.w*a.w;
    }
    #pragma unroll 8
    for (int i = 0; i < 128; i++){
      float4 a = attnT4[i*64+lane]; float4 w = W4[128+i];
      a0 += w.x*a.x; a1 += w.y*a.y; a2 += w.z*a.z; a3 += w.w*a.w;
    }
    float v = (a0+a1)+(a2+a3) + comb_b[n];
    xc3T[((n>>2)<<8) + (lane<<2) + (n&3)] = v;
  } else {                            // gates: u 0..519
    int u = gw - 512;
    int which = u >= 260;
    int j = which ? u - 260 : u;
    const float* Wih = which ? wWih : rWih;
    const float* Whh = which ? wWhh : rWhh;
    const float4* hT4 = which ? whInT4 : rhInT4;
    float acc0=0.f, acc1=0.f, acc2=0.f, acc3=0.f;
    #pragma unroll 4
    for (int kq = 0; kq < 16; kq++){
      float4 a;
      a.x = preT[((which<<6)+4*kq+0)*64+lane];
      a.y = preT[((which<<6)+4*kq+1)*64+lane];
      a.z = preT[((which<<6)+4*kq+2)*64+lane];
      a.w = preT[((which<<6)+4*kq+3)*64+lane];
      acc0 += dot4(((const float4*)(Wih + (long)(0*HC+j)*64))[kq], a);
      acc1 += dot4(((const float4*)(Wih + (long)(1*HC+j)*64))[kq], a);
      acc2 += dot4(((const float4*)(Wih + (long)(2*HC+j)*64))[kq], a);
      acc3 += dot4(((const float4*)(Wih + (long)(3*HC+j)*64))[kq], a);
    }
    #pragma unroll 4
    for (int kq = 0; kq < 65; kq++){
      float4 a = hT4[kq*64+lane];
      acc0 += dot4(((const float4*)(Whh + (long)(0*HC+j)*HC))[kq], a);
      acc1 += dot4(((const float4*)(Whh + (long)(1*HC+j)*HC))[kq], a);
      acc2 += dot4(((const float4*)(Whh + (long)(2*HC+j)*HC))[kq], a);
      acc3 += dot4(((const float4*)(Whh + (long)(3*HC+j)*HC))[kq], a);
    }
    const float* bih = which ? wbih : rbih;
    const float* bhh = which ? wbhh : rbhh;
    acc0 += bih[0*HC+j] + bhh[0*HC+j];
    acc1 += bih[1*HC+j] + bhh[1*HC+j];
    acc2 += bih[2*HC+j] + bhh[2*HC+j];
    acc3 += bih[3*HC+j] + bhh[3*HC+j];
    float cprev = (which ? wcT : rcT)[j*64+lane];
    float c2 = sigmoidf(acc1)*cprev + sigmoidf(acc0)*tanhf(acc2);
    (which ? whT : rhT)[j*64+lane] = sigmoidf(acc3)*tanhf(c2);
  }
}

// ---------------- [8] addressing + read_in + new_memory (T inputs). grid (64,2) -------
__global__ __launch_bounds__(128) void k_addr_mem(const float* __restrict__ rhT,
                                                  const float* __restrict__ whT,
                                                  const float* __restrict__ rheads,
                                                  const float* __restrict__ wheads,
                                                  const float* __restrict__ mem,
                                                  float* __restrict__ xc3T,
                                                  float* __restrict__ nmem){
  int which = blockIdx.y;
  int b = blockIdx.x, m = threadIdx.x;
  const float* hcT = which ? whT : rhT;
  const float* heads0 = which ? wheads : rheads;
  const float* mr = mem + ((long)b*MM + m)*DD;
  float s = 0.f, q = 0.f;
  #pragma unroll 8
  for (int d = 0; d < DD; d++){ float v = mr[d]; s += v; q += v*v; }
  float key  = hcT[m*64 + b];
  float kstr = expf(hcT[64*64 + b]);
  float gate = sigmoidf(hcT[65*64 + b]);
  float nk = fmaxf(fabsf(key)*8.0f, EPSF);
  float nm = fmaxf(sqrtf(q), EPSF);
  float z  = kstr * (key*s) / (nk*nm);
  __shared__ float sm[2], ss[2];
  __shared__ float wsh[128], weL[128], waL[128];
  float mx = wave_max(z);
  if ((m & 63) == 0) sm[m>>6] = mx;
  __syncthreads();
  mx = fmaxf(sm[0], sm[1]);
  float e = expf(z - mx);
  float w = wave_sum(e);
  if ((m & 63) == 0) ss[m>>6] = w;
  __syncthreads();
  float content = e / (ss[0] + ss[1]);
  float wv = gate*content + (1.0f - gate)*heads0[m];   // heads[0]: batch-0 row broadcast
  wsh[m] = wv;
  if (which){
    weL[m] = sigmoidf(whT[(68+m)*64 + b]);
    waL[m] = sigmoidf(whT[(132+m)*64 + b]);
  }
  __syncthreads();
  if (!which){
    if (m < DD){
      float acc = 0.f;
      #pragma unroll 8
      for (int mm = 0; mm < MM; mm++) acc += wsh[mm] * mem[((long)b*MM + mm)*DD + m];
      xc3T[((128 + (m>>2))<<8) + (b<<2) + (m&3)] = acc;    // feature 512+m
    }
  } else {
    for (int idx = m; idx < MM*DD; idx += 128){
      int mm = idx >> 6;
      nmem[(long)b*8192 + idx] = mem[(long)b*8192 + idx]*(1.0f - wsh[mm]*weL[mm]) + wsh[mm]*waL[mm];
    }
  }
}

// ---------------- [9] blg main LSTM: 512 units, K=1088 ([xc3T 576 | h0 512]) ----------
__global__ __launch_bounds__(256) void k_blg_lstm(const float4* __restrict__ xc3T4,
    const float4* __restrict__ h0T4, const float* __restrict__ c0Tp,
    const float* __restrict__ lWih, const float* __restrict__ lWhh,
    const float* __restrict__ bih, const float* __restrict__ bhh,
    float* __restrict__ h1T, float* __restrict__ c1T){
  int lane = threadIdx.x & 63;
  int j = __builtin_amdgcn_readfirstlane(blockIdx.x*4 + (threadIdx.x >> 6));
  float acc0=0.f, acc1=0.f, acc2=0.f, acc3=0.f;
  #pragma unroll 4
  for (int kq = 0; kq < 144; kq++){
    float4 a = xc3T4[kq*64+lane];
    acc0 += dot4(((const float4*)(lWih + (long)(0*HH+j)*576))[kq], a);
    acc1 += dot4(((const float4*)(lWih + (long)(1*HH+j)*576))[kq], a);
    acc2 += dot4(((const float4*)(lWih + (long)(2*HH+j)*576))[kq], a);
    acc3 += dot4(((const float4*)(lWih + (long)(3*HH+j)*576))[kq], a);
  }
  #pragma unroll 4
  for (int kq = 0; kq < 128; kq++){
    float4 a = h0T4[kq*64+lane];
    acc0 += dot4(((const float4*)(lWhh + (long)(0*HH+j)*HH))[kq], a);
    acc1 += dot4(((const float4*)(lWhh + (long)(1*HH+j)*HH))[kq], a);
    acc2 += dot4(((const float4*)(lWhh + (long)(2*HH+j)*HH))[kq], a);
    acc3 += dot4(((const float4*)(lWhh + (long)(3*HH+j)*HH))[kq], a);
  }
  acc0 += bih[0*HH+j] + bhh[0*HH+j];
  acc1 += bih[1*HH+j] + bhh[1*HH+j];
  acc2 += bih[2*HH+j] + bhh[2*HH+j];
  acc3 += bih[3*HH+j] + bhh[3*HH+j];
  float cprev = c0Tp[j*64+lane];
  float c2 = sigmoidf(acc1)*cprev + sigmoidf(acc0)*tanhf(acc2);
  h1T[j*64+lane] = sigmoidf(acc3)*tanhf(c2);
  c1T[j*64+lane] = c2;
}

// ---------------- [10] unpack h1,c1,c1b to standard layout ----------------
__global__ void k_unpack(const float* __restrict__ h1T, const float* __restrict__ c1T,
                         float* __restrict__ h1, float* __restrict__ c1,
                         unsigned short* __restrict__ c1b){
  int t = blockIdx.x*256 + threadIdx.x;      // 32768
  int b = t >> 9, j = t & 511;
  float c2 = c1T[j*64 + b];
  h1[t] = h1T[j*64 + b];
  c1[t] = c2;
  c1b[t] = bf16_rne(c2);
}

// ---------------- [11] logits: bf16 MFMA, burst global_load_lds W staging -------------
__global__ __launch_bounds__(128) void k_logits_mfma(const unsigned short* __restrict__ Ab,
                                                     const float* __restrict__ W,
                                                     const float* __restrict__ bias,
                                                     float* __restrict__ C){
  __shared__ float lds[16384];             // 64 KB: 2 waves x 8192 floats
  int wid = threadIdx.x >> 6, lane = threadIdx.x & 63;
  int strip = blockIdx.x*2 + wid;          // 3125 strips of 16 n
  if (strip >= 3125) return;
  int nl = lane & 15;
  int q  = lane >> 4;
  int n  = strip*16 + nl;
  const float* Wlane = W + (long)n*HH + q*4;
  int base = wid*8192;

  #pragma unroll
  for (int ci = 0; ci < 32; ci++)
    __builtin_amdgcn_global_load_lds((CGV*)(Wlane + ci*16),
        (LV*)&lds[base + ci*256], 16, 0, 0);
  asm volatile("s_waitcnt vmcnt(0)" ::: "memory");
  __builtin_amdgcn_sched_barrier(0);

  const bf16x8* A0 = (const bf16x8*)Ab + (long)(0*16 + nl)*64 + q;
  const bf16x8* A1 = (const bf16x8*)Ab + (long)(1*16 + nl)*64 + q;
  const bf16x8* A2 = (const bf16x8*)Ab + (long)(2*16 + nl)*64 + q;
  const bf16x8* A3 = (const bf16x8*)Ab + (long)(3*16 + nl)*64 + q;
  f32x4 acc0 = {0.f,0.f,0.f,0.f}, acc1 = acc0, acc2 = acc0, acc3 = acc0;

  #pragma unroll
  for (int ks = 0; ks < 16; ks++){
    int off = base + (ks*2 + (q>>1))*256 + (q&1)*128 + nl*4;
    float4 w0 = *(const float4*)&lds[off];
    float4 w1 = *(const float4*)&lds[off + 64];
    bf16x8 bf;
    bf[0] = (short)bf16_rne(w0.x); bf[1] = (short)bf16_rne(w0.y);
    bf[2] = (short)bf16_rne(w0.z); bf[3] = (short)bf16_rne(w0.w);
    bf[4] = (short)bf16_rne(w1.x); bf[5] = (short)bf16_rne(w1.y);
    bf[6] = (short)bf16_rne(w1.z); bf[7] = (short)bf16_rne(w1.w);
    bf16x8 a0 = A0[ks*4];
    bf16x8 a1 = A1[ks*4];
    bf16x8 a2 = A2[ks*4];
    bf16x8 a3 = A3[ks*4];
    acc0 = __builtin_amdgcn_mfma_f32_16x16x32_bf16(a0, bf, acc0, 0, 0, 0);
    acc1 = __builtin_amdgcn_mfma_f32_16x16x32_bf16(a1, bf, acc1, 0, 0, 0);
    acc2 = __builtin_amdgcn_mfma_f32_16x16x32_bf16(a2, bf, acc2, 0, 0, 0);
    acc3 = __builtin_amdgcn_mfma_f32_16x16x32_bf16(a3, bf, acc3, 0, 0, 0);
  }
  float bv = bias[n];
  #pragma unroll
  for (int r = 0; r < 4; r++){
    int m = q*4 + r;
    C[(long)(m     )*VV + n] = acc0[r] + bv;
    C[(long)(m + 16)*VV + n] = acc1[r] + bv;
    C[(long)(m + 32)*VV + n] = acc2[r] + bv;
    C[(long)(m + 48)*VV + n] = acc3[r] + bv;
  }
}

// ---------------- [12-14] 3-stage log_softmax over V ----------------
__global__ __launch_bounds__(256) void k_ls1(const float* __restrict__ lp,
                                             float* __restrict__ pm, float* __restrict__ ps){
  int b = blockIdx.y, c = blockIdx.x, t = threadIdx.x;   // grid (25, 64)
  const float* row = lp + (long)b*VV + c*2000;
  float mx = -INFINITY;
  for (int i = t; i < 2000; i += 256) mx = fmaxf(mx, row[i]);
  __shared__ float sm[4], ss[4];
  mx = wave_max(mx);
  if ((t & 63) == 0) sm[t>>6] = mx;
  __syncthreads();
  mx = fmaxf(fmaxf(sm[0], sm[1]), fmaxf(sm[2], sm[3]));
  float s = 0.f;
  for (int i = t; i < 2000; i += 256) s += expf(row[i] - mx);
  s = wave_sum(s);
  if ((t & 63) == 0) ss[t>>6] = s;
  __syncthreads();
  if (t == 0){ pm[b*25 + c] = mx; ps[b*25 + c] = ss[0]+ss[1]+ss[2]+ss[3]; }
}

__global__ void k_ls2(const float* __restrict__ pm, const float* __restrict__ ps,
                      float* __restrict__ lse){
  int b = threadIdx.x;    // 64
  float m = -INFINITY;
  for (int c = 0; c < 25; c++) m = fmaxf(m, pm[b*25 + c]);
  float s = 0.f;
  for (int c = 0; c < 25; c++) s += ps[b*25 + c]*expf(pm[b*25 + c] - m);
  lse[b] = m + logf(s);
}

__global__ void k_ls3(float* __restrict__ lp, const float* __restrict__ lse){
  int idx = blockIdx.x*256 + threadIdx.x;
  if (idx >= BB*VV) return;
  int b = idx / VV;
  lp[idx] -= lse[b];
}

extern "C" void kernel_launch(void* const* d_in, const int* in_sizes, int n_in,
                              void* d_out, int out_size, void* d_ws, size_t ws_size,
                              hipStream_t stream) {
  const int*   ids     = (const int*)  d_in[0];
  const float* h0      = (const float*)d_in[1];
  const float* c0      = (const float*)d_in[2];
  const float* enc     = (const float*)d_in[3];
  const float* cov     = (const float*)d_in[5];
  const float* mem     = (const float*)d_in[6];
  const float* rheads  = (const float*)d_in[7];
  const float* wheads  = (const float*)d_in[8];
  const float* read_h  = (const float*)d_in[9];
  const float* read_c  = (const float*)d_in[10];
  const float* write_h = (const float*)d_in[11];
  const float* write_c = (const float*)d_in[12];
  const float* emb     = (const float*)d_in[13];
  const float* attn_W  = (const float*)d_in[14];
  const float* attn_b  = (const float*)d_in[15];
  const float* cov_W   = (const float*)d_in[16];
  const float* state_W = (const float*)d_in[17];
  const float* comb_W  = (const float*)d_in[18];
  const float* comb_b  = (const float*)d_in[19];
  const float* rpre_W  = (const float*)d_in[20];
  const float* rpre_b  = (const float*)d_in[21];
  const float* wpre_W  = (const float*)d_in[22];
  const float* wpre_b  = (const float*)d_in[23];
  const float* r_Wih   = (const float*)d_in[24];
  const float* r_Whh   = (const float*)d_in[25];
  const float* r_bih   = (const float*)d_in[26];
  const float* r_bhh   = (const float*)d_in[27];
  const float* w_Wih   = (const float*)d_in[28];
  const float* w_Whh   = (const float*)d_in[29];
  const float* w_bih   = (const float*)d_in[30];
  const float* w_bhh   = (const float*)d_in[31];
  const float* l_Wih   = (const float*)d_in[32];
  const float* l_Whh   = (const float*)d_in[33];
  const float* l_bih   = (const float*)d_in[34];
  const float* l_bhh   = (const float*)d_in[35];
  const float* out_W   = (const float*)d_in[36];
  const float* out_b   = (const float*)d_in[37];

  float* out  = (float*)d_out;
  float* lp   = out;                 // (64, 50000)
  float* h1   = out + 3200000;       // (64, 512)
  float* c1   = h1 + 32768;          // (64, 512)
  float* nmem = c1 + 32768;          // (64, 128, 64)
  float* ncov = nmem + 524288;       // (64, 400)

  float* w = (float*)d_ws;
  float* embT4  = w;                 // 32768
  float* h0T4   = embT4 + 32768;     // 32768
  float* c0T4   = h0T4 + 32768;      // 32768
  float* c0Tp   = c0T4 + 32768;      // 32768
  float* rhInT4 = c0Tp + 32768;      // 16640
  float* whInT4 = rhInT4 + 16640;    // 16640
  float* rcT    = whInT4 + 16640;    // 16640
  float* wcT    = rcT + 16640;       // 16640
  float* memT4  = wcT + 16640;       // 524288  (aliased: U attn partials after k_blgA)
  float* U      = memT4;             // alias — memT4 dead after [2], U born at [5]
  float* iaT    = memT4 + 524288;    // 25600
  float* tsT    = iaT + 25600;       // 25600
  float* tcT    = tsT + 25600;       // 25600
  float* coviaT = tcT + 25600;       // 25600
  float* attnT4 = coviaT + 25600;    // 32768
  float* xc3T   = attnT4 + 32768;    // 36864
  float* preT   = xc3T + 36864;      // 8192
  float* rhT    = preT + 8192;       // 16640
  float* whT    = rhT + 16640;       // 16640
  float* h1T    = whT + 16640;       // 32768
  float* c1T    = h1T + 32768;       // 32768
  float* pm     = c1T + 32768;       // 1600
  float* ps     = pm + 1600;         // 1600
  float* lse    = ps + 1600;         // 64
  unsigned short* c1b = (unsigned short*)(lse + 64);   // 32768 bf16
  // total: 1,020,608 floats = 4.08 MB (< 4.15 MB round-0 high-water)

  // [1] pack transposed activations
  k_pack<<<707, 256, 0, stream>>>(ids, emb, h0, c0, read_h, write_h, read_c, write_c, mem,
      (float4*)embT4, (float4*)h0T4, (float4*)c0T4, c0Tp,
      (float4*)rhInT4, (float4*)whInT4, rcT, wcT, (float4*)memT4);
  // [2] ia + ts + pre (batch-lane, weights once)
  k_blgA<<<232, 256, 0, stream>>>((const float4*)embT4, (const float4*)h0T4,
      (const float4*)c0T4, (const float4*)memT4, attn_W, attn_b, state_W,
      rpre_W, wpre_W, rpre_b, wpre_b, iaT, tsT, preT);
  // [3] cov+ia (T4) + ncov
  k_covia<<<25, 256, 0, stream>>>(cov, iaT, (float4*)coviaT, (float4*)ncov);
  // [4] tc
  k_blg_tc<<<100, 256, 0, stream>>>((const float4*)coviaT, cov_W, tcT);
  // [5][6] attention apply
  k_attn_part<<<dim3(64,16), 256, 0, stream>>>(iaT, tsT, tcT, enc, U);
  k_attn_reduce<<<32, 256, 0, stream>>>((const float4*)U, (float4*)attnT4);
  // [7] comb + head gates/LSTM
  k_blgB<<<258, 256, 0, stream>>>((const float4*)embT4, (const float4*)attnT4,
      comb_W, comb_b, preT, (const float4*)rhInT4, (const float4*)whInT4, rcT, wcT,
      r_Wih, r_Whh, r_bih, r_bhh, w_Wih, w_Whh, w_bih, w_bhh, xc3T, rhT, whT);
  // [8] addressing + read_in + new_memory
  k_addr_mem<<<dim3(64,2), 128, 0, stream>>>(rhT, whT, rheads, wheads, mem, xc3T, nmem);
  // [9] main LSTM
  k_blg_lstm<<<128, 256, 0, stream>>>((const float4*)xc3T, (const float4*)h0T4, c0Tp,
      l_Wih, l_Whh, l_bih, l_bhh, h1T, c1T);
  // [10] unpack h1/c1/c1b
  k_unpack<<<128, 256, 0, stream>>>(h1T, c1T, h1, c1, c1b);
  // [11] output projection + [12-14] log_softmax
  k_logits_mfma<<<1563, 128, 0, stream>>>(c1b, out_W, out_b, lp);
  k_ls1<<<dim3(25,64), 256, 0, stream>>>(lp, pm, ps);
  k_ls2<<<1, 64, 0, stream>>>(pm, ps, lse);
  k_ls3<<<12500, 256, 0, stream>>>(lp, lse);
}